// Round 19
// baseline (165.719 us; speedup 1.0000x reference)
//
#include <hip/hip_runtime.h>

typedef __attribute__((ext_vector_type(8))) short s16x8;
typedef __attribute__((ext_vector_type(4))) short s16x4;
typedef __attribute__((ext_vector_type(4))) float fx4;

__device__ inline unsigned short f2bf(float f) {
  unsigned u = __float_as_uint(f);
  u += 0x7fffu + ((u >> 16) & 1u);
  return (unsigned short)(u >> 16);
}
__device__ inline float bf2f(unsigned short s) {
  return __uint_as_float(((unsigned)s) << 16);
}

#define GLDS16(gp, lp) \
  __builtin_amdgcn_global_load_lds((const __attribute__((address_space(1))) void*)(gp), \
                                   (__attribute__((address_space(3))) void*)(lp), 16, 0, 0)

// ---------------- cast_x (blk<4096) + weight prep (blk>=4096; 320 blocks).
__global__ __launch_bounds__(256) void cast_x_k(const float* __restrict__ x,
                                                unsigned short* __restrict__ xb,
                                                unsigned short* __restrict__ xT,
                                                float* __restrict__ s_part,
                                                const float* __restrict__ w,
                                                const float* __restrict__ wp,
                                                unsigned short* __restrict__ wkT,
                                                unsigned short* __restrict__ wvb,
                                                unsigned short* __restrict__ wpb) {
  __shared__ unsigned short lt[64 * 66];
  __shared__ float red[64 * 4];
  int blk = blockIdx.x;
  int t = threadIdx.x;
  if (blk >= 4096) {
    int wblk = blk - 4096;
    if (wblk < 64) {
      int rt = wblk >> 3, ct = wblk & 7;
      int rn = t >> 2, seg = (t & 3) * 16;
      const float* src = w + (size_t)(ct * 64 + rn) * 1536 + 512 + rt * 64 + seg;
#pragma unroll
      for (int k = 0; k < 16; ++k) lt[(seg + k) * 66 + rn] = f2bf(src[k]);
      __syncthreads();
      int j = t >> 2, nseg = (t & 3) * 16;
      unsigned short* o = wkT + (size_t)(rt * 64 + j) * 512 + ct * 64 + nseg;
      *(s16x8*)&o[0] = *(s16x8*)&lt[j * 66 + nseg];
      *(s16x8*)&o[8] = *(s16x8*)&lt[j * 66 + nseg + 8];
    } else if (wblk < 192) {
      int o = (wblk - 64) * 2048 + t * 8;
      int c = o >> 9, e = o & 511;
      const float* src = w + (size_t)c * 1536 + 1024 + e;
      unsigned short h[8];
#pragma unroll
      for (int i = 0; i < 8; ++i) h[i] = f2bf(src[i]);
      *(s16x8*)&wvb[o] = *(s16x8*)&h[0];
    } else {
      int o = (wblk - 192) * 2048 + t * 8;
      unsigned short h[8];
#pragma unroll
      for (int i = 0; i < 8; ++i) h[i] = f2bf(wp[o + i]);
      *(s16x8*)&wpb[o] = *(s16x8*)&h[0];
    }
    return;
  }
  int b = blk >> 9, r = blk & 511, nt = r >> 3, ct = r & 7;
  int n0 = nt * 64, c0 = ct * 64;
  int rn = t >> 2, seg = (t & 3) * 16;
  const float* xp = x + ((size_t)b * 4096 + n0 + rn) * 512 + c0 + seg;
  fx4 v0 = *(const fx4*)&xp[0], v1 = *(const fx4*)&xp[4];
  fx4 v2 = *(const fx4*)&xp[8], v3 = *(const fx4*)&xp[12];
  unsigned short h[16];
  h[0]=f2bf(v0[0]); h[1]=f2bf(v0[1]); h[2]=f2bf(v0[2]); h[3]=f2bf(v0[3]);
  h[4]=f2bf(v1[0]); h[5]=f2bf(v1[1]); h[6]=f2bf(v1[2]); h[7]=f2bf(v1[3]);
  h[8]=f2bf(v2[0]); h[9]=f2bf(v2[1]); h[10]=f2bf(v2[2]); h[11]=f2bf(v2[3]);
  h[12]=f2bf(v3[0]); h[13]=f2bf(v3[1]); h[14]=f2bf(v3[2]); h[15]=f2bf(v3[3]);
  unsigned short* xbo = xb + ((size_t)b * 4096 + n0 + rn) * 512 + c0 + seg;
  *(s16x8*)&xbo[0] = *(s16x8*)&h[0];
  *(s16x8*)&xbo[8] = *(s16x8*)&h[8];
#pragma unroll
  for (int k = 0; k < 16; ++k) lt[(seg + k) * 66 + rn] = h[k];
  __syncthreads();
  {
    int c = t & 63, q = t >> 6;
    float p = 0.f;
#pragma unroll
    for (int i = 0; i < 16; ++i) p += bf2f(lt[c * 66 + q * 16 + i]);
    red[c * 4 + q] = p;
  }
  __syncthreads();
  if (t < 64) {
    float s = red[t * 4] + red[t * 4 + 1] + red[t * 4 + 2] + red[t * 4 + 3];
    s_part[((size_t)(b * 64 + nt)) * 512 + c0 + t] = s;
  }
  int c = t >> 2, nseg = (t & 3) * 16;
  unsigned short* xto = xT + ((size_t)b * 512 + c0 + c) * 4096 + n0 + nseg;
  *(s16x8*)&xto[0] = *(s16x8*)&lt[c * 66 + nseg];
  *(s16x8*)&xto[8] = *(s16x8*)&lt[c * 66 + nseg + 8];
}

// ---------------- depth-2 counted-vmcnt GEMM (modes 0, 2).
// MODE 0 (G): split-K 4 (K=1024, R13-exact chain), full 16 tiles/(ks,b);
//             grid 544 (512 G-tiles + 32 ub blocks).
// MODE 2 (Wcomb): grid 136 (8 bias2 blocks).
template <int MODE>
__global__ __launch_bounds__(256, 4) void gemm_k(
    const unsigned short* __restrict__ A0, const unsigned short* __restrict__ B0,
    const float* __restrict__ bias, unsigned short* __restrict__ obf,
    float* __restrict__ of32, const float* __restrict__ wf) {
  constexpr int LD = (MODE == 0) ? 4096 : 512;
  constexpr int KSTEPS = (MODE == 0) ? 32 : 16;
  constexpr int NWG = (MODE == 0) ? 544 : 136;
  __shared__ alignas(16) unsigned short As[2][128 * 32];
  __shared__ alignas(16) unsigned short Bs[2][128 * 32];
  int tid = threadIdx.x, wave = tid >> 6, lane = tid & 63;
  int l15 = lane & 15, l16 = lane >> 4;
  int wr = wave >> 1, wc = wave & 1;

  int bid = (blockIdx.x & 7) * (NWG >> 3) + (blockIdx.x >> 3);

  if (MODE == 0 && bid >= 512) {        // ---- ub role (32 blocks)
    float* sb = (float*)As;
    int ubid = bid - 512;
    int b = ubid >> 2, jq = ubid & 3;
    int t = tid;
#pragma unroll
    for (int cc = 0; cc < 2; ++cc) {
      int c = cc * 256 + t;
      float a = 0.f;
      for (int nt = 0; nt < 64; ++nt)
        a += bias[((size_t)(b * 64 + nt)) * 512 + c];   // bias = s_part
      sb[c] = a;
    }
    __syncthreads();
    int j = jq * 256 + t;
    float ua = 0.f;
    for (int c = 0; c < 512; ++c)
      ua += sb[c] * wf[(size_t)c * 1536 + j];           // wf = w_qkv
    ((float*)obf)[b * 1024 + j] = ua;                   // obf = (ushort*)u
    return;
  }
  if (MODE == 2 && bid >= 128) {        // ---- bias2 role (8 blocks)
    float* bv = (float*)As;
    int b = bid - 128;
    int t = tid;
    bv[t] = bias[1024 + t];                             // bias = b_qkv
    bv[t + 256] = bias[1280 + t];
    __syncthreads();
#pragma unroll
    for (int jj = 0; jj < 2; ++jj) {
      int j = jj * 256 + t;
      const unsigned short* wrow = &A0[((size_t)(b * 512 + j)) << 9];  // weffT
      float s = 0.f;
      for (int e = 0; e < 512; e += 8) {
        s16x8 v = *(const s16x8*)&wrow[e];
#pragma unroll
        for (int q = 0; q < 8; ++q) s += bv[e + q] * bf2f((unsigned short)v[q]);
      }
      of32[b * 512 + j] = wf[j] + s;                    // wf = b_p, of32 = bias_out
    }
    return;
  }

  int b = 0, mt = 0, nt = 0, ks = 0;
  if (MODE == 0) {
    ks = bid >> 7; int r = bid & 127; b = r >> 4; int tt = r & 15;
    mt = tt >> 2; nt = tt & 3;
  }
  else { b = bid >> 4; mt = (bid >> 2) & 3; nt = bid & 3; }

  const unsigned short* Ab;
  const unsigned short* Bb;
  if (MODE == 0) { Ab = A0 + ((size_t)b * 512 + mt * 128) * 4096 + ks * 1024;
                   Bb = A0 + ((size_t)b * 512 + nt * 128) * 4096 + ks * 1024; }
  else { Ab = A0 + ((size_t)b * 512 + mt * 128) * 512;
         Bb = B0 + (size_t)nt * 128 * 512; }

  fx4 acc[4][4];
#pragma unroll
  for (int i = 0; i < 4; ++i)
#pragma unroll
    for (int j = 0; j < 4; ++j) acc[i][j] = (fx4){0.f, 0.f, 0.f, 0.f};

  int smr = wave * 16 + (lane >> 2);
  int skk = (((lane & 3) ^ ((lane >> 3) & 3))) * 8;
  const unsigned short* agp = Ab + (size_t)smr * LD + skk;
  const unsigned short* bgp = Bb + (size_t)smr * LD + skk;
  int ldsoff = wave * 512;

#define STAGE(buf, kt_)                                          \
  do {                                                           \
    int k0_ = (kt_) * 32;                                        \
    GLDS16(agp + k0_, &As[buf][ldsoff]);                         \
    GLDS16(agp + (size_t)64 * LD + k0_, &As[buf][ldsoff + 2048]);\
    GLDS16(bgp + k0_, &Bs[buf][ldsoff]);                         \
    GLDS16(bgp + (size_t)64 * LD + k0_, &Bs[buf][ldsoff + 2048]);\
  } while (0)

  STAGE(0, 0);
  STAGE(1, 1);                           // depth-2: 8 loads in flight

  int g = (l15 >> 1) & 3;
  int pa = (l16 ^ g) << 3;

  for (int kt = 0; kt < KSTEPS; ++kt) {
    if (kt < KSTEPS - 1) asm volatile("s_waitcnt vmcnt(4)" ::: "memory");
    else                 asm volatile("s_waitcnt vmcnt(0)" ::: "memory");
    __builtin_amdgcn_s_barrier();

    int cur = kt & 1;
    s16x8 af[4], bf[4];
#pragma unroll
    for (int mi = 0; mi < 4; ++mi)
      af[mi] = *(const s16x8*)&As[cur][(wr * 64 + mi * 16 + l15) * 32 + pa];
#pragma unroll
    for (int nj = 0; nj < 4; ++nj)
      bf[nj] = *(const s16x8*)&Bs[cur][(wc * 64 + nj * 16 + l15) * 32 + pa];
#pragma unroll
    for (int mi = 0; mi < 4; ++mi)
#pragma unroll
      for (int nj = 0; nj < 4; ++nj)
        acc[mi][nj] = __builtin_amdgcn_mfma_f32_16x16x32_bf16(af[mi], bf[nj], acc[mi][nj], 0, 0, 0);

    asm volatile("s_waitcnt lgkmcnt(0)" ::: "memory");
    __builtin_amdgcn_s_barrier();
    if (kt < KSTEPS - 2) STAGE(cur, kt + 2);   // refill freed buffer
  }
#undef STAGE

  int R0 = mt * 128 + wr * 64, C0 = nt * 128 + wc * 64;
#pragma unroll
  for (int mi = 0; mi < 4; ++mi)
#pragma unroll
    for (int nj = 0; nj < 4; ++nj) {
      int gc = C0 + nj * 16 + l15;
#pragma unroll
      for (int r = 0; r < 4; ++r) {
        int gr = R0 + mi * 16 + l16 * 4 + r;
        float val = acc[mi][nj][r];
        if (MODE == 0) {
          of32[(((size_t)(ks * 8 + b)) * 512 + gr) * 512 + gc] = val;
        } else {
          obf[((size_t)(b * 512 + gr)) * 512 + gc] = f2bf(val);
        }
      }
    }
}

// ---------------- gemm1: GWT[b][e][c] = sum_c' wkT[e][c'] * G_b[c][c'] with
// G summed on-the-fly from 4 Gpart partials (gsum fused; bit-exact: same
// ((p0+p1)+p2)+p3 order + same f2bf before MFMA). A via GLDS; B reg-staged
// into the SAME swizzled LDS slots (slot s at row R holds chunk s^g(R)).
// grid 128 = b*16 + mt*4 + nt (XCD swizzle -> batch b per XCD).
__global__ __launch_bounds__(256, 2) void gemm1_k(
    const unsigned short* __restrict__ wkT, const float* __restrict__ Gpart,
    unsigned short* __restrict__ GWT) {
  __shared__ alignas(16) unsigned short As[2][128 * 32];
  __shared__ alignas(16) unsigned short Bs[2][128 * 32];
  int tid = threadIdx.x, wave = tid >> 6, lane = tid & 63;
  int l15 = lane & 15, l16 = lane >> 4;
  int wr = wave >> 1, wc = wave & 1;
  int bid = (blockIdx.x & 7) * 16 + (blockIdx.x >> 3);
  int b = bid >> 4, mt = (bid >> 2) & 3, nt = bid & 3;

  const unsigned short* Ab = wkT + (size_t)mt * 128 * 512;
  const float* gb = Gpart + ((size_t)b * 512 + nt * 128) * 512;

  fx4 acc[4][4];
#pragma unroll
  for (int i = 0; i < 4; ++i)
#pragma unroll
    for (int j = 0; j < 4; ++j) acc[i][j] = (fx4){0.f, 0.f, 0.f, 0.f};

  int smr = wave * 16 + (lane >> 2);
  int skk = (((lane & 3) ^ ((lane >> 3) & 3))) * 8;
  const unsigned short* agp = Ab + (size_t)smr * 512 + skk;
  int ldsoff = wave * 512;

  int brow = tid >> 1;                       // 0..127
  int bg = ((brow & 15) >> 1) & 3;
  int s0 = (tid & 1) * 2;                    // slots s0, s0+1
  const float* gsrc = gb + (size_t)brow * 512;
  int c0 = ((s0 ^ bg)) * 8, c1 = (((s0 + 1) ^ bg)) * 8;

#define ASTAGE(buf, kt_)                                             \
  do { int k0_ = (kt_) * 32;                                         \
    GLDS16(agp + k0_, &As[buf][ldsoff]);                             \
    GLDS16(agp + (size_t)64 * 512 + k0_, &As[buf][ldsoff + 2048]);   \
  } while (0)

  fx4 bl[16];
#define BISSUE(kt_)                                                  \
  do { const float* p_ = gsrc + (kt_) * 32;                          \
    _Pragma("unroll") for (int pp = 0; pp < 4; ++pp) {               \
      bl[pp * 2 + 0]     = *(const fx4*)&p_[pp * 2097152 + c0];      \
      bl[pp * 2 + 1]     = *(const fx4*)&p_[pp * 2097152 + c0 + 4];  \
      bl[8 + pp * 2 + 0] = *(const fx4*)&p_[pp * 2097152 + c1];      \
      bl[8 + pp * 2 + 1] = *(const fx4*)&p_[pp * 2097152 + c1 + 4];  \
    }                                                                \
  } while (0)

#define BWRITE(buf)                                                          \
  do {                                                                       \
    fx4 sa = ((bl[0] + bl[2]) + bl[4]) + bl[6];                              \
    fx4 sb_ = ((bl[1] + bl[3]) + bl[5]) + bl[7];                             \
    fx4 sc = ((bl[8] + bl[10]) + bl[12]) + bl[14];                           \
    fx4 sd = ((bl[9] + bl[11]) + bl[13]) + bl[15];                           \
    unsigned short hh[16];                                                   \
    hh[0]=f2bf(sa[0]);  hh[1]=f2bf(sa[1]);  hh[2]=f2bf(sa[2]);  hh[3]=f2bf(sa[3]);   \
    hh[4]=f2bf(sb_[0]); hh[5]=f2bf(sb_[1]); hh[6]=f2bf(sb_[2]); hh[7]=f2bf(sb_[3]);  \
    hh[8]=f2bf(sc[0]);  hh[9]=f2bf(sc[1]);  hh[10]=f2bf(sc[2]); hh[11]=f2bf(sc[3]);  \
    hh[12]=f2bf(sd[0]); hh[13]=f2bf(sd[1]); hh[14]=f2bf(sd[2]); hh[15]=f2bf(sd[3]);  \
    *(s16x8*)&Bs[buf][brow * 32 + s0 * 8] = *(s16x8*)&hh[0];                 \
    *(s16x8*)&Bs[buf][brow * 32 + (s0 + 1) * 8] = *(s16x8*)&hh[8];           \
  } while (0)

  // prologue: tile 0 into buf 0
  ASTAGE(0, 0);
  BISSUE(0);
  BWRITE(0);
  __syncthreads();     // drains A-GLDS (vmcnt) + ds_writes (lgkm)

  int g = (l15 >> 1) & 3;
  int pa = (l16 ^ g) << 3;

  for (int kt = 0; kt < 16; ++kt) {
    int cur = kt & 1;
    if (kt < 15) { ASTAGE(cur ^ 1, kt + 1); BISSUE(kt + 1); }

    s16x8 af[4], bf[4];
#pragma unroll
    for (int mi = 0; mi < 4; ++mi)
      af[mi] = *(const s16x8*)&As[cur][(wr * 64 + mi * 16 + l15) * 32 + pa];
#pragma unroll
    for (int nj = 0; nj < 4; ++nj)
      bf[nj] = *(const s16x8*)&Bs[cur][(wc * 64 + nj * 16 + l15) * 32 + pa];
#pragma unroll
    for (int mi = 0; mi < 4; ++mi)
#pragma unroll
      for (int nj = 0; nj < 4; ++nj)
        acc[mi][nj] = __builtin_amdgcn_mfma_f32_16x16x32_bf16(af[mi], bf[nj], acc[mi][nj], 0, 0, 0);

    if (kt < 15) BWRITE(cur ^ 1);
    __syncthreads();   // next buffer (A-GLDS + B ds_writes) ready past here
  }
#undef ASTAGE
#undef BISSUE
#undef BWRITE

  int R0 = mt * 128 + wr * 64, C0 = nt * 128 + wc * 64;
#pragma unroll
  for (int mi = 0; mi < 4; ++mi)
#pragma unroll
    for (int nj = 0; nj < 4; ++nj) {
      int gc = C0 + nj * 16 + l15;
#pragma unroll
      for (int r = 0; r < 4; ++r) {
        int gr = R0 + mi * 16 + l16 * 4 + r;
        GWT[((size_t)(b * 512 + gr)) * 512 + gc] = f2bf(acc[mi][nj][r]);
      }
    }
}

// ---------------- gemm3: 256x256 tile, BK=64, 8 waves, 8-phase counted-vmcnt.
__global__ __launch_bounds__(512, 2) void gemm3_k(
    const unsigned short* __restrict__ A0, const unsigned short* __restrict__ B0,
    const float* __restrict__ bias, float* __restrict__ outp) {
  __shared__ alignas(16) unsigned short As[2][16384];
  __shared__ alignas(16) unsigned short Bs[2][16384];
  int tid = threadIdx.x, wave = tid >> 6, lane = tid & 63;
  int l15 = lane & 15, l16 = lane >> 4;
  int wr = wave >> 2, wc = wave & 3;

  int bid = (blockIdx.x & 7) * 32 + (blockIdx.x >> 3);
  int b = bid >> 5, rr_ = bid & 31, mt = rr_ >> 1, nt = rr_ & 1;

  const unsigned short* Ab = A0 + ((size_t)b * 4096 + mt * 256) * 512;
  const unsigned short* Bb = B0 + ((size_t)b * 512 + nt * 256) * 512;

  fx4 acc[8][4];
#pragma unroll
  for (int i = 0; i < 8; ++i)
#pragma unroll
    for (int j = 0; j < 4; ++j) acc[i][j] = (fx4){0.f, 0.f, 0.f, 0.f};

  int srow = tid >> 3;
  int chk = ((tid & 7) ^ (srow & 7)) * 8;
  const unsigned short* agp = Ab + (size_t)srow * 512 + chk;
  const unsigned short* bgp = Bb + (size_t)srow * 512 + chk;
  int wofs = wave * 512;

#define SG_A(nb, tt, h, q) GLDS16(agp + (size_t)((h)*128 + (q)*64) * 512 + (tt)*64, \
                                  &As[nb][((h)*128 + (q)*64) * 64 + wofs])
#define SG_B(nb, tt, h, q) GLDS16(bgp + (size_t)((h)*128 + (q)*64) * 512 + (tt)*64, \
                                  &Bs[nb][((h)*128 + (q)*64) * 64 + wofs])

  SG_A(0, 0, 0, 0); SG_A(0, 0, 0, 1); SG_A(0, 0, 1, 0); SG_A(0, 0, 1, 1);
  SG_B(0, 0, 0, 0); SG_B(0, 0, 0, 1); SG_B(0, 0, 1, 0); SG_B(0, 0, 1, 1);

  s16x8 af[4], bf[4];
  int aro = wr * 128, bro = wc * 64;

#define RD_A(buf, qm, ks)                                                              \
  {                                                                                    \
    _Pragma("unroll")                                                                  \
    for (int i = 0; i < 4; ++i)                                                        \
      af[i] = *(const s16x8*)&As[buf][(aro + (qm)*64 + i*16 + l15) * 64 +              \
                                      ((((ks)*4 + l16) ^ (l15 & 7)) * 8)];             \
  }
#define RD_B(buf, ks)                                                                  \
  {                                                                                    \
    _Pragma("unroll")                                                                  \
    for (int j = 0; j < 4; ++j)                                                        \
      bf[j] = *(const s16x8*)&Bs[buf][(bro + j*16 + l15) * 64 +                        \
                                      ((((ks)*4 + l16) ^ (l15 & 7)) * 8)];             \
  }
#define MM(qm)                                                                         \
  {                                                                                    \
    __builtin_amdgcn_s_setprio(1);                                                     \
    _Pragma("unroll")                                                                  \
    for (int i = 0; i < 4; ++i)                                                        \
      _Pragma("unroll")                                                                \
      for (int j = 0; j < 4; ++j)                                                      \
        acc[(qm)*4 + i][j] =                                                           \
            __builtin_amdgcn_mfma_f32_16x16x32_bf16(af[i], bf[j], acc[(qm)*4 + i][j], 0, 0, 0); \
    __builtin_amdgcn_s_setprio(0);                                                     \
  }

  for (int t = 0; t < 8; ++t) {
    int buf = t & 1, nb = buf ^ 1;
    if (t < 7) {
      SG_A(nb, t + 1, 0, 0); SG_A(nb, t + 1, 0, 1);
      asm volatile("s_waitcnt vmcnt(2)" ::: "memory");
    } else {
      asm volatile("s_waitcnt vmcnt(0)" ::: "memory");
    }
    __builtin_amdgcn_s_barrier();
    RD_A(buf, 0, 0); RD_B(buf, 0);
    MM(0);
    __builtin_amdgcn_s_barrier();
    RD_A(buf, 1, 0);
    if (t < 7) { SG_A(nb, t + 1, 1, 0); SG_A(nb, t + 1, 1, 1); }
    __builtin_amdgcn_s_barrier();
    MM(1);
    __builtin_amdgcn_s_barrier();
    RD_A(buf, 0, 1); RD_B(buf, 1);
    if (t < 7) { SG_B(nb, t + 1, 0, 0); SG_B(nb, t + 1, 0, 1); }
    __builtin_amdgcn_s_barrier();
    MM(0);
    __builtin_amdgcn_s_barrier();
    RD_A(buf, 1, 1);
    if (t < 7) { SG_B(nb, t + 1, 1, 0); SG_B(nb, t + 1, 1, 1); }
    __builtin_amdgcn_s_barrier();
    MM(1);
    __builtin_amdgcn_s_barrier();
  }
#undef SG_A
#undef SG_B
#undef RD_A
#undef RD_B
#undef MM

  int crow0 = mt * 256 + wr * 128, ccol0 = nt * 256 + wc * 64;
#pragma unroll
  for (int am = 0; am < 8; ++am)
#pragma unroll
    for (int nj = 0; nj < 4; ++nj) {
      int gc = ccol0 + nj * 16 + l15;
      float bsv = bias[b * 512 + gc];
#pragma unroll
      for (int r = 0; r < 4; ++r) {
        int gr = crow0 + am * 16 + l16 * 4 + r;
        outp[((size_t)(b * 4096 + gr)) * 512 + gc] = acc[am][nj][r] + bsv;
      }
    }
}

// ---------------- s_k: partial S over c-chunk. grid 512 = bh*8 + cch.
__global__ __launch_bounds__(256) void s_k(const float* __restrict__ wq,
                                           const unsigned short* __restrict__ GWT,
                                           float* __restrict__ sp) {
  __shared__ alignas(16) float Ws[64 * 68];
  __shared__ alignas(16) float Gs[64 * 68];
  int bid = blockIdx.x;
  int bh = bid >> 3, cch = bid & 7;
  int b = bh >> 3, h = bh & 7;
  int t = threadIdx.x;
  int cr = t >> 2, sg = (t & 3) * 16;
  const float* wsrc = wq + (size_t)(cch * 64 + cr) * 1536 + h * 64 + sg;
#pragma unroll
  for (int kk = 0; kk < 16; ++kk) Ws[cr * 68 + sg + kk] = wsrc[kk];
  const unsigned short* gsrc = GWT + ((size_t)b * 512 + h * 64 + cr) * 512 + cch * 64 + sg;
#pragma unroll
  for (int kk = 0; kk < 16; ++kk) Gs[(sg + kk) * 68 + cr] = bf2f(gsrc[kk]);
  __syncthreads();
  int dg = t >> 4, eg = t & 15;
  float acc[4][4] = {{0.f}};
  for (int cc = 0; cc < 64; ++cc) {
    fx4 wv = *(const fx4*)&Ws[cc * 68 + dg * 4];
    fx4 pv = *(const fx4*)&Gs[cc * 68 + eg * 4];
#pragma unroll
    for (int i = 0; i < 4; ++i)
#pragma unroll
      for (int j = 0; j < 4; ++j) acc[i][j] += wv[i] * pv[j];
  }
  float* o = sp + (size_t)bid * 4096;
#pragma unroll
  for (int i = 0; i < 4; ++i)
#pragma unroll
    for (int j = 0; j < 4; ++j) o[(dg * 4 + i) * 64 + eg * 4 + j] = acc[i][j];
}

// ---------------- softmax + Weff. grid 256 = bh*4 + jblk.
__global__ __launch_bounds__(256) void softmax_weff_k(
    const float* __restrict__ sp, const unsigned short* __restrict__ wpb,
    const float* __restrict__ temp, const float* __restrict__ b_qkv,
    const float* __restrict__ u, unsigned short* __restrict__ weffT) {
  __shared__ alignas(16) float S[64 * 64];
  __shared__ alignas(16) unsigned short wps[64 * 128];
  int bh = blockIdx.x >> 2, jblk = blockIdx.x & 3;
  int b = bh >> 3, h = bh & 7;
  int tid = threadIdx.x;
  float tval = temp[h];
  for (int i = tid * 4; i < 4096; i += 1024) {
    fx4 s = {0.f, 0.f, 0.f, 0.f};
    for (int seg = 0; seg < 8; ++seg)
      s += *(const fx4*)&sp[((size_t)(bh * 8 + seg)) * 4096 + i];
    int d = i >> 6, e0 = i & 63;
    float bq = b_qkv[h * 64 + d];
    float uq = u[b * 1024 + h * 64 + d];
#pragma unroll
    for (int jj = 0; jj < 4; ++jj) {
      int e = e0 + jj;
      float bk = b_qkv[512 + h * 64 + e];
      float ksum = u[b * 1024 + 512 + h * 64 + e] + 4096.0f * bk;
      s[jj] += bq * ksum + bk * uq;
    }
    s *= tval;
    *(fx4*)&S[i] = s;
  }
  for (int i = tid * 8; i < 8192; i += 2048) {
    int d = i >> 7, c = i & 127;
    *(s16x8*)&wps[i] = *(const s16x8*)&wpb[(size_t)(h * 64 + d) * 512 + jblk * 128 + c];
  }
  __syncthreads();
  if (tid < 64) {
    float* row = &S[tid * 64];
    float mx = row[0];
    for (int e = 1; e < 64; ++e) mx = fmaxf(mx, row[e]);
    float sum = 0.f;
    for (int e = 0; e < 64; ++e) { float p = __expf(row[e] - mx); row[e] = p; sum += p; }
    float inv = 1.f / sum;
    for (int e = 0; e < 64; ++e) row[e] *= inv;
  }
  __syncthreads();
  int jg = tid >> 4, eg = tid & 15;
  int j0 = jg * 8;
  float a[4][8];
#pragma unroll
  for (int i = 0; i < 4; ++i)
#pragma unroll
    for (int j = 0; j < 8; ++j) a[i][j] = 0.f;
  for (int d = 0; d < 64; ++d) {
    fx4 at = *(const fx4*)&S[d * 64 + eg * 4];
    s16x8 wv = *(const s16x8*)&wps[d * 128 + j0];
    float wf8[8];
#pragma unroll
    for (int j = 0; j < 8; ++j) wf8[j] = bf2f((unsigned short)wv[j]);
#pragma unroll
    for (int i = 0; i < 4; ++i)
#pragma unroll
      for (int j = 0; j < 8; ++j) a[i][j] += at[i] * wf8[j];
  }
  int jglob = jblk * 128 + j0;
#pragma unroll
  for (int j = 0; j < 8; ++j) {
    unsigned short h4[4];
#pragma unroll
    for (int i = 0; i < 4; ++i) h4[i] = f2bf(a[i][j]);
    *(s16x4*)&weffT[(((size_t)b * 512 + jglob + j) << 9) + h * 64 + eg * 4] = *(s16x4*)&h4[0];
  }
}

// ---------------- host ----------------
extern "C" void kernel_launch(void* const* d_in, const int* in_sizes, int n_in,
                              void* d_out, int out_size, void* d_ws, size_t ws_size,
                              hipStream_t stream) {
  const float* x      = (const float*)d_in[0];
  const float* w_qkv  = (const float*)d_in[1];
  const float* b_qkv  = (const float*)d_in[2];
  const float* w_p    = (const float*)d_in[3];
  const float* b_p    = (const float*)d_in[4];
  const float* temp   = (const float*)d_in[5];
  float* out = (float*)d_out;
  char* ws = (char*)d_ws;

  unsigned short* xb     = (unsigned short*)(ws + 0);           // 32 MB
  unsigned short* xT     = (unsigned short*)(ws + 33554432);    // 32 MB (dead after G)
  float*          Gpart  = (float*)(ws + 67108864);             // 33.5 MB f32 [4][8][512][512]
  unsigned short* GWT    = (unsigned short*)(ws + 138412032);   // 4 MB
  float*          sp     = (float*)(ws + 142606336);            // 8 MB
  unsigned short* wkT    = (unsigned short*)(ws + 150994944);   // 512 KB
  unsigned short* wvb    = (unsigned short*)(ws + 151519232);   // 512 KB
  unsigned short* wpb    = (unsigned short*)(ws + 152043520);   // 512 KB
  float*          u      = (float*)(ws + 152567808);            // 32 KB
  float*          bias_o = (float*)(ws + 152600576);            // 16 KB
  float*          s_part = (float*)(ws + 152616960);            // 1 MB
  unsigned short* weffT  = (unsigned short*)(ws + 33554432);    // 4 MB (xT region)
  unsigned short* wcombT = (unsigned short*)(ws + 37748736);    // 4 MB (xT region)

  cast_x_k<<<4416, 256, 0, stream>>>(x, xb, xT, s_part, w_qkv, w_p, wkT, wvb, wpb);
  gemm_k<0><<<544, 256, 0, stream>>>(xT, nullptr, s_part, (unsigned short*)u, Gpart, w_qkv);
  gemm1_k<<<128, 256, 0, stream>>>(wkT, Gpart, GWT);
  s_k<<<512, 256, 0, stream>>>(w_qkv, GWT, sp);
  softmax_weff_k<<<256, 256, 0, stream>>>(sp, wpb, temp, b_qkv, u, weffT);
  gemm_k<2><<<136, 256, 0, stream>>>(weffT, wvb, b_qkv, wcombT, bias_o, b_p);
  gemm3_k<<<256, 512, 0, stream>>>(xb, wcombT, bias_o, out);
}

// Round 20
// 137.067 us; speedup vs baseline: 1.2090x; 1.2090x over previous
//
#include <hip/hip_runtime.h>

typedef __attribute__((ext_vector_type(8))) short s16x8;
typedef __attribute__((ext_vector_type(4))) short s16x4;
typedef __attribute__((ext_vector_type(4))) float fx4;

__device__ inline unsigned short f2bf(float f) {
  unsigned u = __float_as_uint(f);
  u += 0x7fffu + ((u >> 16) & 1u);
  return (unsigned short)(u >> 16);
}
__device__ inline float bf2f(unsigned short s) {
  return __uint_as_float(((unsigned)s) << 16);
}

#define GLDS16(gp, lp) \
  __builtin_amdgcn_global_load_lds((const __attribute__((address_space(1))) void*)(gp), \
                                   (__attribute__((address_space(3))) void*)(lp), 16, 0, 0)

// ---------------- cast_x (blk<4096) + weight prep (blk>=4096; 320 blocks).
__global__ __launch_bounds__(256) void cast_x_k(const float* __restrict__ x,
                                                unsigned short* __restrict__ xb,
                                                unsigned short* __restrict__ xT,
                                                float* __restrict__ s_part,
                                                const float* __restrict__ w,
                                                const float* __restrict__ wp,
                                                unsigned short* __restrict__ wkT,
                                                unsigned short* __restrict__ wvb,
                                                unsigned short* __restrict__ wpb) {
  __shared__ unsigned short lt[64 * 66];
  __shared__ float red[64 * 4];
  int blk = blockIdx.x;
  int t = threadIdx.x;
  if (blk >= 4096) {
    int wblk = blk - 4096;
    if (wblk < 64) {
      int rt = wblk >> 3, ct = wblk & 7;
      int rn = t >> 2, seg = (t & 3) * 16;
      const float* src = w + (size_t)(ct * 64 + rn) * 1536 + 512 + rt * 64 + seg;
#pragma unroll
      for (int k = 0; k < 16; ++k) lt[(seg + k) * 66 + rn] = f2bf(src[k]);
      __syncthreads();
      int j = t >> 2, nseg = (t & 3) * 16;
      unsigned short* o = wkT + (size_t)(rt * 64 + j) * 512 + ct * 64 + nseg;
      *(s16x8*)&o[0] = *(s16x8*)&lt[j * 66 + nseg];
      *(s16x8*)&o[8] = *(s16x8*)&lt[j * 66 + nseg + 8];
    } else if (wblk < 192) {
      int o = (wblk - 64) * 2048 + t * 8;
      int c = o >> 9, e = o & 511;
      const float* src = w + (size_t)c * 1536 + 1024 + e;
      unsigned short h[8];
#pragma unroll
      for (int i = 0; i < 8; ++i) h[i] = f2bf(src[i]);
      *(s16x8*)&wvb[o] = *(s16x8*)&h[0];
    } else {
      int o = (wblk - 192) * 2048 + t * 8;
      unsigned short h[8];
#pragma unroll
      for (int i = 0; i < 8; ++i) h[i] = f2bf(wp[o + i]);
      *(s16x8*)&wpb[o] = *(s16x8*)&h[0];
    }
    return;
  }
  int b = blk >> 9, r = blk & 511, nt = r >> 3, ct = r & 7;
  int n0 = nt * 64, c0 = ct * 64;
  int rn = t >> 2, seg = (t & 3) * 16;
  const float* xp = x + ((size_t)b * 4096 + n0 + rn) * 512 + c0 + seg;
  fx4 v0 = *(const fx4*)&xp[0], v1 = *(const fx4*)&xp[4];
  fx4 v2 = *(const fx4*)&xp[8], v3 = *(const fx4*)&xp[12];
  unsigned short h[16];
  h[0]=f2bf(v0[0]); h[1]=f2bf(v0[1]); h[2]=f2bf(v0[2]); h[3]=f2bf(v0[3]);
  h[4]=f2bf(v1[0]); h[5]=f2bf(v1[1]); h[6]=f2bf(v1[2]); h[7]=f2bf(v1[3]);
  h[8]=f2bf(v2[0]); h[9]=f2bf(v2[1]); h[10]=f2bf(v2[2]); h[11]=f2bf(v2[3]);
  h[12]=f2bf(v3[0]); h[13]=f2bf(v3[1]); h[14]=f2bf(v3[2]); h[15]=f2bf(v3[3]);
  unsigned short* xbo = xb + ((size_t)b * 4096 + n0 + rn) * 512 + c0 + seg;
  *(s16x8*)&xbo[0] = *(s16x8*)&h[0];
  *(s16x8*)&xbo[8] = *(s16x8*)&h[8];
#pragma unroll
  for (int k = 0; k < 16; ++k) lt[(seg + k) * 66 + rn] = h[k];
  __syncthreads();
  {
    int c = t & 63, q = t >> 6;
    float p = 0.f;
#pragma unroll
    for (int i = 0; i < 16; ++i) p += bf2f(lt[c * 66 + q * 16 + i]);
    red[c * 4 + q] = p;
  }
  __syncthreads();
  if (t < 64) {
    float s = red[t * 4] + red[t * 4 + 1] + red[t * 4 + 2] + red[t * 4 + 3];
    s_part[((size_t)(b * 64 + nt)) * 512 + c0 + t] = s;
  }
  int c = t >> 2, nseg = (t & 3) * 16;
  unsigned short* xto = xT + ((size_t)b * 512 + c0 + c) * 4096 + n0 + nseg;
  *(s16x8*)&xto[0] = *(s16x8*)&lt[c * 66 + nseg];
  *(s16x8*)&xto[8] = *(s16x8*)&lt[c * 66 + nseg + 8];
}

// ---------------- 2-phase GEMM (modes 0..3). R12-best configuration.
// MODE 0 (G): split-K 4, symmetric tiles mt<=nt; grid 352 (320 + 32 ub).
// MODE 1 (GWT): grid 128.  MODE 2 (Wcomb): grid 136 (8 bias2).  MODE 3: grid 1024.
template <int MODE>
__global__ __launch_bounds__(256, 4) void gemm_k(
    const unsigned short* __restrict__ A0, const unsigned short* __restrict__ B0,
    const float* __restrict__ bias, unsigned short* __restrict__ obf,
    float* __restrict__ of32, const float* __restrict__ wf) {
  constexpr int LD = (MODE == 0) ? 4096 : 512;
  constexpr int KSTEPS = (MODE == 0) ? 32 : 16;
  constexpr int NWG = (MODE == 0) ? 352 : (MODE == 3) ? 1024 : (MODE == 2) ? 136 : 128;
  __shared__ alignas(16) unsigned short As[2][128 * 32];
  __shared__ alignas(16) unsigned short Bs[2][128 * 32];
  int tid = threadIdx.x, wave = tid >> 6, lane = tid & 63;
  int l15 = lane & 15, l16 = lane >> 4;
  int wr = wave >> 1, wc = wave & 1;

  int bid = (blockIdx.x & 7) * (NWG >> 3) + (blockIdx.x >> 3);

  if (MODE == 0 && bid >= 320) {        // ---- ub role (32 blocks)
    float* sb = (float*)As;
    int ubid = bid - 320;
    int b = ubid >> 2, jq = ubid & 3;
    int t = tid;
#pragma unroll
    for (int cc = 0; cc < 2; ++cc) {
      int c = cc * 256 + t;
      float a = 0.f;
      for (int nt = 0; nt < 64; ++nt)
        a += bias[((size_t)(b * 64 + nt)) * 512 + c];   // bias = s_part
      sb[c] = a;
    }
    __syncthreads();
    int j = jq * 256 + t;
    float ua = 0.f;
    for (int c = 0; c < 512; ++c)
      ua += sb[c] * wf[(size_t)c * 1536 + j];           // wf = w_qkv
    ((float*)obf)[b * 1024 + j] = ua;                   // obf = (ushort*)u
    return;
  }
  if (MODE == 2 && bid >= 128) {        // ---- bias2 role (8 blocks)
    float* bv = (float*)As;
    int b = bid - 128;
    int t = tid;
    bv[t] = bias[1024 + t];                             // bias = b_qkv
    bv[t + 256] = bias[1280 + t];
    __syncthreads();
#pragma unroll
    for (int jj = 0; jj < 2; ++jj) {
      int j = jj * 256 + t;
      const unsigned short* wrow = &A0[((size_t)(b * 512 + j)) << 9];  // weffT
      float s = 0.f;
      for (int e = 0; e < 512; e += 8) {
        s16x8 v = *(const s16x8*)&wrow[e];
#pragma unroll
        for (int q = 0; q < 8; ++q) s += bv[e + q] * bf2f((unsigned short)v[q]);
      }
      of32[b * 512 + j] = wf[j] + s;                    // wf = b_p, of32 = bias_out
    }
    return;
  }

  int b = 0, mt = 0, nt = 0, ks = 0;
  if (MODE == 0) {
    const int TTM[10] = {0, 0, 0, 0, 1, 1, 1, 2, 2, 3};
    const int TTN[10] = {0, 1, 2, 3, 1, 2, 3, 2, 3, 3};
    ks = bid / 80; int r = bid - ks * 80; b = r / 10; int tt = r - b * 10;
    mt = TTM[tt]; nt = TTN[tt];
  }
  else if (MODE == 3) { b = bid >> 7; int r = bid & 127; mt = r >> 2; nt = r & 3; }
  else { b = bid >> 4; mt = (bid >> 2) & 3; nt = bid & 3; }

  const unsigned short* Ab;
  const unsigned short* Bb;
  if (MODE == 0) { Ab = A0 + ((size_t)b * 512 + mt * 128) * 4096 + ks * 1024;
                   Bb = A0 + ((size_t)b * 512 + nt * 128) * 4096 + ks * 1024; }
  else if (MODE == 1) { Ab = A0 + (size_t)mt * 128 * 512;
                        Bb = B0 + ((size_t)b * 512 + nt * 128) * 512; }
  else if (MODE == 2) { Ab = A0 + ((size_t)b * 512 + mt * 128) * 512;
                        Bb = B0 + (size_t)nt * 128 * 512; }
  else { Ab = A0 + ((size_t)b * 4096 + mt * 128) * 512;
         Bb = B0 + ((size_t)b * 512 + nt * 128) * 512; }

  fx4 acc[4][4];
#pragma unroll
  for (int i = 0; i < 4; ++i)
#pragma unroll
    for (int j = 0; j < 4; ++j) acc[i][j] = (fx4){0.f, 0.f, 0.f, 0.f};

  int smr = wave * 16 + (lane >> 2);
  int skk = (((lane & 3) ^ ((lane >> 3) & 3))) * 8;
  const unsigned short* agp = Ab + (size_t)smr * LD + skk;
  const unsigned short* bgp = Bb + (size_t)smr * LD + skk;
  int ldsoff = wave * 512;

#define STAGE(buf, kt_)                                          \
  do {                                                           \
    int k0_ = (kt_) * 32;                                        \
    GLDS16(agp + k0_, &As[buf][ldsoff]);                         \
    GLDS16(agp + (size_t)64 * LD + k0_, &As[buf][ldsoff + 2048]);\
    GLDS16(bgp + k0_, &Bs[buf][ldsoff]);                         \
    GLDS16(bgp + (size_t)64 * LD + k0_, &Bs[buf][ldsoff + 2048]);\
  } while (0)

  STAGE(0, 0);
  asm volatile("s_waitcnt vmcnt(0)" ::: "memory");
  __builtin_amdgcn_s_barrier();

  int g = (l15 >> 1) & 3;
  int pa = (l16 ^ g) << 3;

  for (int kt = 0; kt < KSTEPS; ++kt) {
    int cur = kt & 1;
    if (kt < KSTEPS - 1) STAGE(cur ^ 1, kt + 1);

    s16x8 af[4], bf[4];
#pragma unroll
    for (int mi = 0; mi < 4; ++mi)
      af[mi] = *(const s16x8*)&As[cur][(wr * 64 + mi * 16 + l15) * 32 + pa];
#pragma unroll
    for (int nj = 0; nj < 4; ++nj)
      bf[nj] = *(const s16x8*)&Bs[cur][(wc * 64 + nj * 16 + l15) * 32 + pa];
#pragma unroll
    for (int mi = 0; mi < 4; ++mi)
#pragma unroll
      for (int nj = 0; nj < 4; ++nj)
        acc[mi][nj] = __builtin_amdgcn_mfma_f32_16x16x32_bf16(af[mi], bf[nj], acc[mi][nj], 0, 0, 0);

    asm volatile("s_waitcnt vmcnt(0)" ::: "memory");
    __builtin_amdgcn_s_barrier();
  }
#undef STAGE

  int R0 = mt * 128 + wr * 64, C0 = nt * 128 + wc * 64;
#pragma unroll
  for (int mi = 0; mi < 4; ++mi)
#pragma unroll
    for (int nj = 0; nj < 4; ++nj) {
      int gc = C0 + nj * 16 + l15;
#pragma unroll
      for (int r = 0; r < 4; ++r) {
        int gr = R0 + mi * 16 + l16 * 4 + r;
        float val = acc[mi][nj][r];
        if (MODE == 0) {
          of32[(((size_t)(ks * 8 + b)) * 512 + gr) * 512 + gc] = val;
        } else if (MODE == 1) {
          obf[((size_t)(b * 512 + gr)) * 512 + gc] = f2bf(val);
        } else if (MODE == 2) {
          obf[((size_t)(b * 512 + gr)) * 512 + gc] = f2bf(val);
        } else {
          of32[((size_t)(b * 4096 + gr)) * 512 + gc] = val + bias[b * 512 + gc];
        }
      }
    }
}

// ---------------- gsum: G16[b][r][c] = bf16(sum_ks Gpart). Symmetric source:
// if 128-block(r) > 128-block(c), mirror from upper triangle (LDS transpose).
// grid 512 = b*64 + rt*8 + ct (64x64 tiles).
__global__ __launch_bounds__(256) void gsum_k(const float* __restrict__ Gpart,
                                              unsigned short* __restrict__ G16) {
  __shared__ float ts[64 * 65];
  int blk = blockIdx.x;
  int b = blk >> 6, rt = (blk >> 3) & 7, ct = blk & 7;
  int t = threadIdx.x;
  int r0 = t >> 4, c0 = (t & 15) * 4;
  bool lower = (rt >> 1) > (ct >> 1);
  if (!lower) {
#pragma unroll
    for (int rr = 0; rr < 4; ++rr) {
      int row = rr * 16 + r0;
      size_t base = (((size_t)b * 512) + rt * 64 + row) * 512 + ct * 64 + c0;
      fx4 a = {0.f, 0.f, 0.f, 0.f};
#pragma unroll
      for (int p = 0; p < 4; ++p) a += *(const fx4*)&Gpart[(size_t)p * 2097152 + base];
      unsigned short h4[4];
#pragma unroll
      for (int i = 0; i < 4; ++i) h4[i] = f2bf(a[i]);
      *(s16x4*)&G16[(((size_t)b * 512) + rt * 64 + row) * 512 + ct * 64 + c0] = *(s16x4*)&h4[0];
    }
  } else {
#pragma unroll
    for (int rr = 0; rr < 4; ++rr) {
      int srow = rr * 16 + r0;
      size_t base = (((size_t)b * 512) + ct * 64 + srow) * 512 + rt * 64 + c0;
      fx4 a = {0.f, 0.f, 0.f, 0.f};
#pragma unroll
      for (int p = 0; p < 4; ++p) a += *(const fx4*)&Gpart[(size_t)p * 2097152 + base];
#pragma unroll
      for (int i = 0; i < 4; ++i) ts[(c0 + i) * 65 + srow] = a[i];
    }
    __syncthreads();
#pragma unroll
    for (int rr = 0; rr < 4; ++rr) {
      int row = rr * 16 + r0;
      unsigned short h4[4];
#pragma unroll
      for (int i = 0; i < 4; ++i) h4[i] = f2bf(ts[row * 65 + c0 + i]);
      *(s16x4*)&G16[(((size_t)b * 512) + rt * 64 + row) * 512 + ct * 64 + c0] = *(s16x4*)&h4[0];
    }
  }
}

// ---------------- s_k: partial S over c-chunk. grid 512 = bh*8 + cch.
__global__ __launch_bounds__(256) void s_k(const float* __restrict__ wq,
                                           const unsigned short* __restrict__ GWT,
                                           float* __restrict__ sp) {
  __shared__ alignas(16) float Ws[64 * 68];
  __shared__ alignas(16) float Gs[64 * 68];
  int bid = blockIdx.x;
  int bh = bid >> 3, cch = bid & 7;
  int b = bh >> 3, h = bh & 7;
  int t = threadIdx.x;
  int cr = t >> 2, sg = (t & 3) * 16;
  const float* wsrc = wq + (size_t)(cch * 64 + cr) * 1536 + h * 64 + sg;
#pragma unroll
  for (int kk = 0; kk < 16; ++kk) Ws[cr * 68 + sg + kk] = wsrc[kk];
  const unsigned short* gsrc = GWT + ((size_t)b * 512 + h * 64 + cr) * 512 + cch * 64 + sg;
#pragma unroll
  for (int kk = 0; kk < 16; ++kk) Gs[(sg + kk) * 68 + cr] = bf2f(gsrc[kk]);
  __syncthreads();
  int dg = t >> 4, eg = t & 15;
  float acc[4][4] = {{0.f}};
  for (int cc = 0; cc < 64; ++cc) {
    fx4 wv = *(const fx4*)&Ws[cc * 68 + dg * 4];
    fx4 pv = *(const fx4*)&Gs[cc * 68 + eg * 4];
#pragma unroll
    for (int i = 0; i < 4; ++i)
#pragma unroll
      for (int j = 0; j < 4; ++j) acc[i][j] += wv[i] * pv[j];
  }
  float* o = sp + (size_t)bid * 4096;
#pragma unroll
  for (int i = 0; i < 4; ++i)
#pragma unroll
    for (int j = 0; j < 4; ++j) o[(dg * 4 + i) * 64 + eg * 4 + j] = acc[i][j];
}

// ---------------- softmax + Weff. grid 256 = bh*4 + jblk. NO atomics; 8B stores.
__global__ __launch_bounds__(256) void softmax_weff_k(
    const float* __restrict__ sp, const unsigned short* __restrict__ wpb,
    const float* __restrict__ temp, const float* __restrict__ b_qkv,
    const float* __restrict__ u, unsigned short* __restrict__ weffT) {
  __shared__ alignas(16) float S[64 * 64];
  __shared__ alignas(16) unsigned short wps[64 * 128];
  int bh = blockIdx.x >> 2, jblk = blockIdx.x & 3;
  int b = bh >> 3, h = bh & 7;
  int tid = threadIdx.x;
  float tval = temp[h];
  for (int i = tid * 4; i < 4096; i += 1024) {
    fx4 s = {0.f, 0.f, 0.f, 0.f};
    for (int seg = 0; seg < 8; ++seg)
      s += *(const fx4*)&sp[((size_t)(bh * 8 + seg)) * 4096 + i];
    int d = i >> 6, e0 = i & 63;
    float bq = b_qkv[h * 64 + d];
    float uq = u[b * 1024 + h * 64 + d];
#pragma unroll
    for (int jj = 0; jj < 4; ++jj) {
      int e = e0 + jj;
      float bk = b_qkv[512 + h * 64 + e];
      float ksum = u[b * 1024 + 512 + h * 64 + e] + 4096.0f * bk;
      s[jj] += bq * ksum + bk * uq;
    }
    s *= tval;
    *(fx4*)&S[i] = s;
  }
  for (int i = tid * 8; i < 8192; i += 2048) {
    int d = i >> 7, c = i & 127;
    *(s16x8*)&wps[i] = *(const s16x8*)&wpb[(size_t)(h * 64 + d) * 512 + jblk * 128 + c];
  }
  __syncthreads();
  if (tid < 64) {
    float* row = &S[tid * 64];
    float mx = row[0];
    for (int e = 1; e < 64; ++e) mx = fmaxf(mx, row[e]);
    float sum = 0.f;
    for (int e = 0; e < 64; ++e) { float p = __expf(row[e] - mx); row[e] = p; sum += p; }
    float inv = 1.f / sum;
    for (int e = 0; e < 64; ++e) row[e] *= inv;
  }
  __syncthreads();
  int jg = tid >> 4, eg = tid & 15;
  int j0 = jg * 8;
  float a[4][8];
#pragma unroll
  for (int i = 0; i < 4; ++i)
#pragma unroll
    for (int j = 0; j < 8; ++j) a[i][j] = 0.f;
  for (int d = 0; d < 64; ++d) {
    fx4 at = *(const fx4*)&S[d * 64 + eg * 4];
    s16x8 wv = *(const s16x8*)&wps[d * 128 + j0];
    float wf8[8];
#pragma unroll
    for (int j = 0; j < 8; ++j) wf8[j] = bf2f((unsigned short)wv[j]);
#pragma unroll
    for (int i = 0; i < 4; ++i)
#pragma unroll
      for (int j = 0; j < 8; ++j) a[i][j] += at[i] * wf8[j];
  }
  int jglob = jblk * 128 + j0;
#pragma unroll
  for (int j = 0; j < 8; ++j) {
    unsigned short h4[4];
#pragma unroll
    for (int i = 0; i < 4; ++i) h4[i] = f2bf(a[i][j]);
    *(s16x4*)&weffT[(((size_t)b * 512 + jglob + j) << 9) + h * 64 + eg * 4] = *(s16x4*)&h4[0];
  }
}

// ---------------- host ----------------
extern "C" void kernel_launch(void* const* d_in, const int* in_sizes, int n_in,
                              void* d_out, int out_size, void* d_ws, size_t ws_size,
                              hipStream_t stream) {
  const float* x      = (const float*)d_in[0];
  const float* w_qkv  = (const float*)d_in[1];
  const float* b_qkv  = (const float*)d_in[2];
  const float* w_p    = (const float*)d_in[3];
  const float* b_p    = (const float*)d_in[4];
  const float* temp   = (const float*)d_in[5];
  float* out = (float*)d_out;
  char* ws = (char*)d_ws;

  unsigned short* xb     = (unsigned short*)(ws + 0);           // 32 MB
  unsigned short* xT     = (unsigned short*)(ws + 33554432);    // 32 MB (dead after G)
  float*          Gpart  = (float*)(ws + 67108864);             // 32 MB f32 [4][8][512][512]
  unsigned short* G16    = (unsigned short*)(ws + 100663296);   // 4 MB
  unsigned short* GWT    = (unsigned short*)(ws + 104857600);   // 4 MB
  float*          sp     = (float*)(ws + 109051904);            // 8 MB
  unsigned short* wkT    = (unsigned short*)(ws + 117440512);   // 512 KB
  unsigned short* wvb    = (unsigned short*)(ws + 117964800);   // 512 KB
  unsigned short* wpb    = (unsigned short*)(ws + 118489088);   // 512 KB
  float*          u      = (float*)(ws + 119013376);            // 32 KB
  float*          bias_o = (float*)(ws + 119046144);            // 16 KB
  float*          s_part = (float*)(ws + 119062528);            // 1 MB, own slot
  unsigned short* weffT  = (unsigned short*)(ws + 33554432);    // 4 MB (xT region)
  unsigned short* wcombT = (unsigned short*)(ws + 37748736);    // 4 MB (xT region)

  cast_x_k<<<4416, 256, 0, stream>>>(x, xb, xT, s_part, w_qkv, w_p, wkT, wvb, wpb);
  gemm_k<0><<<352, 256, 0, stream>>>(xT, nullptr, s_part, (unsigned short*)u, Gpart, w_qkv);
  gsum_k<<<512, 256, 0, stream>>>(Gpart, G16);
  gemm_k<1><<<128, 256, 0, stream>>>(wkT, G16, nullptr, GWT, nullptr, nullptr);
  s_k<<<512, 256, 0, stream>>>(w_qkv, GWT, sp);
  softmax_weff_k<<<256, 256, 0, stream>>>(sp, wpb, temp, b_qkv, u, weffT);
  gemm_k<2><<<136, 256, 0, stream>>>(weffT, wvb, b_qkv, wcombT, bias_o, b_p);
  gemm_k<3><<<1024, 256, 0, stream>>>(xb, wcombT, bias_o, nullptr, out, nullptr);
}